// Round 13
// baseline (1878.799 us; speedup 1.0000x reference)
//
#include <hip/hip_runtime.h>
#include <cstddef>

#define TPB 256

__device__ __forceinline__ float4 relu4(float4 v) {
    v.x = fmaxf(v.x, 0.0f); v.y = fmaxf(v.y, 0.0f);
    v.z = fmaxf(v.z, 0.0f); v.w = fmaxf(v.w, 0.0f);
    return v;
}

// joined ch (g*128 + l): l<64 -> a[n][g*64+l], else b[n][g*64+l-64]
__device__ __forceinline__ const float* pick_src(const float* a, const float* b,
                                                 int n, int g, int l, int HW) {
    return (l < 64) ? a + ((size_t)n * 128 + g * 64 + l) * HW
                    : b + ((size_t)n * 128 + g * 64 + (l - 64)) * HW;
}

// ===========================================================================
// 3x3 s1 p1 grouped conv (groups=2). Tile: (4*OCB) oc x (ROWS*W) px. 256 thr.
// Each thread: OCB oc x J px (strided px -> conflict-free b32 LDS reads).
// ===========================================================================
template<int W, int ROWS, int OCB, bool RELU_IN, bool SPLIT>
__global__ __launch_bounds__(256) void conv3_kernel(
    const float* __restrict__ in, const float* __restrict__ in2,
    const float* __restrict__ wgt, const float* __restrict__ bias,
    float* __restrict__ out, int Cin, int Cout, int relu_out)
{
    constexpr int J = ROWS * W / 64;
    constexpr int OCT = OCB * 4;
    constexpr int NW = OCB / 4;
    constexpr int ICB = 8;
    constexpr int IN_H = ROWS + 2, IN_W2 = W + 8;
    constexpr int W4 = W / 4;
    __shared__ float s_in[ICB][IN_H][IN_W2];
    __shared__ float s_w[ICB * 9 * OCT];

    const int tid = threadIdx.x;
    const int tx = tid & 63, ty = tid >> 6;
    const int n = blockIdx.z, oc0 = blockIdx.y * OCT, r0 = blockIdx.x * ROWS;
    const int icg = Cin >> 1, ocg = Cout >> 1;
    const int g = oc0 / ocg;

    float acc[OCB][J];
    #pragma unroll
    for (int o = 0; o < OCB; ++o) {
        const float b = bias ? bias[oc0 + ty * OCB + o] : 0.0f;
        #pragma unroll
        for (int j = 0; j < J; ++j) acc[o][j] = b;
    }

    const float* inb = SPLIT ? nullptr
                             : in + ((size_t)n * Cin + (size_t)g * icg) * (W * W);

    for (int ic0 = 0; ic0 < icg; ic0 += ICB) {
        __syncthreads();
        for (int i = tid; i < ICB * IN_H * W4; i += 256) {
            const int icl = i / (IN_H * W4);
            const int rem = i - icl * (IN_H * W4);
            const int rr = rem / W4, c4 = rem - rr * W4;
            const int y = r0 - 1 + rr;
            float4 v = make_float4(0.f, 0.f, 0.f, 0.f);
            if ((unsigned)y < (unsigned)W) {
                const float* src = SPLIT ? pick_src(in, in2, n, g, ic0 + icl, W * W)
                                         : inb + (size_t)(ic0 + icl) * (W * W);
                v = *(const float4*)(src + (size_t)y * W + 4 * c4);
            }
            if (RELU_IN) v = relu4(v);
            *(float4*)&s_in[icl][rr][4 + 4 * c4] = v;
        }
        for (int i = tid; i < ICB * IN_H; i += 256) {
            const int icl = i / IN_H, rr = i - icl * IN_H;
            s_in[icl][rr][3] = 0.0f;
            s_in[icl][rr][W + 4] = 0.0f;
        }
        for (int i = tid; i < ICB * 9 * OCT; i += 256) {
            const int ocl = i % OCT, rest = i / OCT;
            const int k = rest % 9, icl = rest / 9;
            s_w[i] = wgt[((size_t)(oc0 + ocl) * icg + (ic0 + icl)) * 9 + k];
        }
        __syncthreads();

        #pragma unroll 1
        for (int icl = 0; icl < ICB; ++icl) {
            const float* swb = s_w + icl * 9 * OCT + ty * OCB;
            #pragma unroll
            for (int ky = 0; ky < 3; ++ky) {
                #pragma unroll
                for (int kx = 0; kx < 3; ++kx) {
                    const int kq = ky * 3 + kx;
                    float4 wv[NW];
                    #pragma unroll
                    for (int u = 0; u < NW; ++u)
                        wv[u] = *(const float4*)(swb + kq * OCT + 4 * u);
                    #pragma unroll
                    for (int j = 0; j < J; ++j) {
                        const int p = j * 64 + tx;
                        const int rr = p / W, cc = p - rr * W;
                        const float v = s_in[icl][rr + ky][cc + 3 + kx];
                        #pragma unroll
                        for (int u = 0; u < NW; ++u) {
                            acc[4 * u + 0][j] = fmaf(wv[u].x, v, acc[4 * u + 0][j]);
                            acc[4 * u + 1][j] = fmaf(wv[u].y, v, acc[4 * u + 1][j]);
                            acc[4 * u + 2][j] = fmaf(wv[u].z, v, acc[4 * u + 2][j]);
                            acc[4 * u + 3][j] = fmaf(wv[u].w, v, acc[4 * u + 3][j]);
                        }
                    }
                }
            }
        }
    }

    const int HWo = W * W;
    float* ob = out + ((size_t)n * Cout + oc0 + ty * OCB) * HWo;
    #pragma unroll
    for (int o = 0; o < OCB; ++o) {
        #pragma unroll
        for (int j = 0; j < J; ++j) {
            const int p = j * 64 + tx;
            const int rr = p / W, cc = p - rr * W;
            float r = acc[o][j];
            if (relu_out) r = fmaxf(r, 0.0f);
            ob[(size_t)o * HWo + (size_t)(r0 + rr) * W + cc] = r;
        }
    }
}

// ===========================================================================
// 4x4 s2 p1 grouped conv (groups=2). W = OUTPUT width; input 2W x 2W.
// ===========================================================================
template<int W, int ROWS>
__global__ __launch_bounds__(256) void conv4s2_kernel(
    const float* __restrict__ in, const float* __restrict__ wgt,
    const float* __restrict__ bias, float* __restrict__ out,
    int Cin, int Cout, int relu_out)
{
    constexpr int J = ROWS * W / 64;
    constexpr int ICB = 4;
    constexpr int IN_H = 2 * ROWS + 2, IN_W2 = 2 * W + 8;
    constexpr int W24 = W / 2;
    __shared__ float s_in[ICB][IN_H][IN_W2];
    __shared__ float s_w[ICB * 16 * 32];

    const int tid = threadIdx.x;
    const int tx = tid & 63, ty = tid >> 6;
    const int n = blockIdx.z, oc0 = blockIdx.y * 32, r0 = blockIdx.x * ROWS;
    const int icg = Cin >> 1, ocg = Cout >> 1;
    const int g = oc0 / ocg;
    const int Hin = 2 * W;

    float acc[8][J];
    #pragma unroll
    for (int o = 0; o < 8; ++o) {
        const float b = bias ? bias[oc0 + ty * 8 + o] : 0.0f;
        #pragma unroll
        for (int j = 0; j < J; ++j) acc[o][j] = b;
    }

    const float* inb = in + ((size_t)n * Cin + (size_t)g * icg) * (Hin * Hin);
    for (int ic0 = 0; ic0 < icg; ic0 += ICB) {
        __syncthreads();
        for (int i = tid; i < ICB * IN_H * W24; i += 256) {
            const int icl = i / (IN_H * W24);
            const int rem = i - icl * (IN_H * W24);
            const int rr = rem / W24, c4 = rem - rr * W24;
            const int y = 2 * r0 - 1 + rr;
            float4 v = make_float4(0.f, 0.f, 0.f, 0.f);
            if ((unsigned)y < (unsigned)Hin)
                v = *(const float4*)(inb + (size_t)(ic0 + icl) * (Hin * Hin)
                                     + (size_t)y * Hin + 4 * c4);
            *(float4*)&s_in[icl][rr][4 + 4 * c4] = v;
        }
        for (int i = tid; i < ICB * IN_H; i += 256) {
            const int icl = i / IN_H, rr = i - icl * IN_H;
            s_in[icl][rr][3] = 0.0f;
            s_in[icl][rr][2 * W + 4] = 0.0f;
        }
        for (int i = tid; i < ICB * 16 * 32; i += 256) {
            const int ocl = i & 31, rest = i >> 5;
            const int k = rest & 15, icl = rest >> 4;
            s_w[i] = wgt[((size_t)(oc0 + ocl) * icg + (ic0 + icl)) * 16 + k];
        }
        __syncthreads();

        #pragma unroll 1
        for (int icl = 0; icl < ICB; ++icl) {
            const float* swb = s_w + icl * 512 + ty * 8;
            #pragma unroll
            for (int ky = 0; ky < 4; ++ky) {
                #pragma unroll
                for (int kx = 0; kx < 4; ++kx) {
                    const int kq = ky * 4 + kx;
                    const float4 wA = *(const float4*)(swb + kq * 32);
                    const float4 wB = *(const float4*)(swb + kq * 32 + 4);
                    #pragma unroll
                    for (int j = 0; j < J; ++j) {
                        const int p = j * 64 + tx;
                        const int rr = p / W, cc = p - rr * W;
                        const float v = s_in[icl][2 * rr + ky][2 * cc + 3 + kx];
                        acc[0][j] = fmaf(wA.x, v, acc[0][j]);
                        acc[1][j] = fmaf(wA.y, v, acc[1][j]);
                        acc[2][j] = fmaf(wA.z, v, acc[2][j]);
                        acc[3][j] = fmaf(wA.w, v, acc[3][j]);
                        acc[4][j] = fmaf(wB.x, v, acc[4][j]);
                        acc[5][j] = fmaf(wB.y, v, acc[5][j]);
                        acc[6][j] = fmaf(wB.z, v, acc[6][j]);
                        acc[7][j] = fmaf(wB.w, v, acc[7][j]);
                    }
                }
            }
        }
    }

    const int HWo = W * W;
    float* ob = out + ((size_t)n * Cout + oc0 + ty * 8) * HWo;
    #pragma unroll
    for (int o = 0; o < 8; ++o) {
        #pragma unroll
        for (int j = 0; j < J; ++j) {
            const int p = j * 64 + tx;
            const int rr = p / W, cc = p - rr * W;
            float r = acc[o][j];
            if (relu_out) r = fmaxf(r, 0.0f);
            ob[(size_t)o * HWo + (size_t)(r0 + rr) * W + cc] = r;
        }
    }
}

// ===========================================================================
// 1x1 grouped conv (pixel GEMM). Tile: 32 oc x PX px.
// ===========================================================================
template<int PX, bool RELU_IN, bool ACC, bool RELU_OUT, bool SPLIT>
__global__ __launch_bounds__(256) void conv1_kernel(
    const float* __restrict__ in, const float* __restrict__ in2,
    const float* __restrict__ wgt, const float* __restrict__ bias,
    float* __restrict__ out, int Cin, int Cout, int HW)
{
    constexpr int J = PX / 64;
    constexpr int PX4 = PX / 4;
    constexpr int ICB = 16;
    __shared__ float s_in[ICB][PX];
    __shared__ float s_w[ICB * 32];

    const int tid = threadIdx.x;
    const int tx = tid & 63, ty = tid >> 6;
    const int n = blockIdx.z, oc0 = blockIdx.y * 32, p0 = blockIdx.x * PX;
    const int icg = Cin >> 1, ocg = Cout >> 1;
    const int g = oc0 / ocg;

    float acc[8][J];
    #pragma unroll
    for (int o = 0; o < 8; ++o) {
        const float b = bias ? bias[oc0 + ty * 8 + o] : 0.0f;
        #pragma unroll
        for (int j = 0; j < J; ++j) acc[o][j] = b;
    }

    const float* inb = SPLIT ? nullptr
                             : in + ((size_t)n * Cin + (size_t)g * icg) * HW + p0;
    for (int ic0 = 0; ic0 < icg; ic0 += ICB) {
        __syncthreads();
        for (int i = tid; i < ICB * PX4; i += 256) {
            const int icl = i / PX4, c4 = i - (i / PX4) * PX4;
            const float* src = SPLIT ? pick_src(in, in2, n, g, ic0 + icl, HW) + p0
                                     : inb + (size_t)(ic0 + icl) * HW;
            float4 v = *(const float4*)(src + 4 * c4);
            if (RELU_IN) v = relu4(v);
            *(float4*)&s_in[icl][4 * c4] = v;
        }
        for (int i = tid; i < ICB * 32; i += 256) {
            const int ocl = i & 31, icl = i >> 5;
            s_w[i] = wgt[(size_t)(oc0 + ocl) * icg + ic0 + icl];
        }
        __syncthreads();

        #pragma unroll 4
        for (int icl = 0; icl < ICB; ++icl) {
            const float4 wA = *(const float4*)(s_w + icl * 32 + ty * 8);
            const float4 wB = *(const float4*)(s_w + icl * 32 + ty * 8 + 4);
            #pragma unroll
            for (int j = 0; j < J; ++j) {
                const float v = s_in[icl][j * 64 + tx];
                acc[0][j] = fmaf(wA.x, v, acc[0][j]);
                acc[1][j] = fmaf(wA.y, v, acc[1][j]);
                acc[2][j] = fmaf(wA.z, v, acc[2][j]);
                acc[3][j] = fmaf(wA.w, v, acc[3][j]);
                acc[4][j] = fmaf(wB.x, v, acc[4][j]);
                acc[5][j] = fmaf(wB.y, v, acc[5][j]);
                acc[6][j] = fmaf(wB.z, v, acc[6][j]);
                acc[7][j] = fmaf(wB.w, v, acc[7][j]);
            }
        }
    }

    float* ob = out + ((size_t)n * Cout + oc0 + ty * 8) * HW + p0;
    #pragma unroll
    for (int o = 0; o < 8; ++o) {
        #pragma unroll
        for (int j = 0; j < J; ++j) {
            const size_t idx = (size_t)o * HW + j * 64 + tx;
            float r = acc[o][j];
            if (ACC) r += ob[idx];
            if (RELU_OUT) r = fmaxf(r, 0.0f);
            ob[idx] = r;
        }
    }
}

// ===========================================================================
// Grouped ConvTranspose2d K4 s2 p1 (groups=2). W = OUTPUT width; input W/2.
// torch layout w: (Cin, Cout/groups, 4, 4). Parity-decomposed taps.
// ===========================================================================
template<int W, int ROWS, int OCT>
__global__ __launch_bounds__(64 * (OCT / 8)) void convt4_kernel(
    const float* __restrict__ in, const float* __restrict__ wgt,
    const float* __restrict__ bias, float* __restrict__ out,
    int Cin, int Cout, int relu_out)
{
    constexpr int NTHR = 64 * (OCT / 8);
    constexpr int PXT  = ROWS * W / 64;
    constexpr int WP   = W / 64;
    constexpr int ICB  = 8;
    constexpr int RIN  = ((ROWS + 1) >> 1) + 2;
    constexpr int CIN  = W / 2 + 2;
    __shared__ float s_in[ICB][RIN][CIN];
    __shared__ float s_w[ICB * 16 * OCT];

    const int tid = threadIdx.x;
    const int tx = tid & 63, ty = tid >> 6;
    const int n = blockIdx.z;
    const int oc0 = blockIdx.y * OCT;
    const int r0 = blockIdx.x * ROWS;
    const int icg = Cin >> 1, ocg = Cout >> 1;
    const int g = oc0 / ocg, of0 = oc0 - g * ocg;
    const int Hin = W / 2;
    const int iy_lo = (r0 - 2) >> 1;

    float acc[8][PXT];
    #pragma unroll
    for (int o = 0; o < 8; ++o) {
        const float b = bias ? bias[oc0 + ty * 8 + o] : 0.0f;
        #pragma unroll
        for (int j = 0; j < PXT; ++j) acc[o][j] = b;
    }

    const float* inb = in + ((size_t)n * Cin + (size_t)g * icg) * (Hin * Hin);
    const int kxl = ((tx + 1) & 1);
    const int hx  = (tx + 1) >> 1;

    for (int ic0 = 0; ic0 < icg; ic0 += ICB) {
        __syncthreads();
        for (int i = tid; i < ICB * RIN * CIN; i += NTHR) {
            const int icl = i / (RIN * CIN);
            const int rem = i - icl * (RIN * CIN);
            const int rr = rem / CIN, cc = rem - rr * CIN;
            const int y = iy_lo + rr, x = cc - 1;
            float v = 0.0f;
            if ((unsigned)y < (unsigned)Hin && (unsigned)x < (unsigned)Hin)
                v = inb[(size_t)(ic0 + icl) * (Hin * Hin) + y * Hin + x];
            s_in[icl][rr][cc] = v;
        }
        for (int i = tid; i < ICB * 16 * OCT; i += NTHR) {
            const int ocl = i & (OCT - 1);
            const int rest = i / OCT;
            const int k = rest & 15, icl = rest >> 4;
            s_w[i] = wgt[((size_t)(g * icg + ic0 + icl) * ocg + of0 + ocl) * 16 + k];
        }
        __syncthreads();

        #pragma unroll 1
        for (int icl = 0; icl < ICB; ++icl) {
            const float* swb = s_w + icl * 16 * OCT + ty * 8;
            #pragma unroll
            for (int tt = 0; tt < 4; ++tt) {
                const int ty2 = tt >> 1, tx2 = tt & 1;
                float4 wp0[2], wp1[2];
                #pragma unroll
                for (int par = 0; par < 2; ++par) {
                    const int koff = ((2 * ty2 + par) * 4 + (kxl + 2 * tx2)) * OCT;
                    wp0[par] = *(const float4*)(swb + koff);
                    wp1[par] = *(const float4*)(swb + koff + 4);
                }
                const int cbase = hx - tx2 + 1;
                #pragma unroll
                for (int j = 0; j < PXT; ++j) {
                    const int row_j = j / WP, m_j = j - row_j * WP;
                    const int pj = (row_j + 1) & 1;
                    const int rloc = (row_j + 1 - pj) / 2 - ty2 + 1;
                    const float v = s_in[icl][rloc][32 * m_j + cbase];
                    const float4 wa = pj ? wp0[1] : wp0[0];
                    const float4 wb = pj ? wp1[1] : wp1[0];
                    acc[0][j] = fmaf(wa.x, v, acc[0][j]);
                    acc[1][j] = fmaf(wa.y, v, acc[1][j]);
                    acc[2][j] = fmaf(wa.z, v, acc[2][j]);
                    acc[3][j] = fmaf(wa.w, v, acc[3][j]);
                    acc[4][j] = fmaf(wb.x, v, acc[4][j]);
                    acc[5][j] = fmaf(wb.y, v, acc[5][j]);
                    acc[6][j] = fmaf(wb.z, v, acc[6][j]);
                    acc[7][j] = fmaf(wb.w, v, acc[7][j]);
                }
            }
        }
    }

    const int HWo = W * W;
    float* ob = out + ((size_t)n * Cout + oc0 + ty * 8) * HWo;
    #pragma unroll
    for (int o = 0; o < 8; ++o) {
        #pragma unroll
        for (int j = 0; j < PXT; ++j) {
            const int row_j = j / WP, m_j = j - row_j * WP;
            float r = acc[o][j];
            if (relu_out) r = fmaxf(r, 0.0f);
            ob[(size_t)o * HWo + (size_t)(r0 + row_j) * W + 64 * m_j + tx] = r;
        }
    }
}

// ===========================================================================
// Fused encoder head (float4)
// ===========================================================================
__global__ void head_kernel(const float* __restrict__ x,
                            const float* __restrict__ dw, const float* __restrict__ db,
                            const float* __restrict__ rw, const float* __restrict__ rb,
                            float* __restrict__ out)
{
    const int idx = blockIdx.x * TPB + threadIdx.x;
    const int HW4 = 16384;
    if (idx >= 8 * 64 * HW4) return;
    const int p4 = idx & (HW4 - 1);
    const int t = idx >> 14;
    const int c = t & 63, n = t >> 6;
    const float4* xb4 = (const float4*)(x + (size_t)n * 4 * 65536);
    float4 v;
    if (c < 32) {
        const float w = dw[c], b = db[c];
        const float4 d = xb4[p4];
        v.x = fmaf(d.x, w, b); v.y = fmaf(d.y, w, b);
        v.z = fmaf(d.z, w, b); v.w = fmaf(d.w, w, b);
    } else {
        const int cc = c - 32;
        const float w0 = rw[cc * 3], w1 = rw[cc * 3 + 1], w2 = rw[cc * 3 + 2];
        const float b = rb[cc];
        const float4 r = xb4[HW4 + p4], g4 = xb4[2 * HW4 + p4], bl = xb4[3 * HW4 + p4];
        v.x = fmaf(bl.x, w2, fmaf(g4.x, w1, fmaf(r.x, w0, b)));
        v.y = fmaf(bl.y, w2, fmaf(g4.y, w1, fmaf(r.y, w0, b)));
        v.z = fmaf(bl.z, w2, fmaf(g4.z, w1, fmaf(r.z, w0, b)));
        v.w = fmaf(bl.w, w2, fmaf(g4.w, w1, fmaf(r.w, w0, b)));
    }
    ((float4*)out)[idx] = relu4(v);
}

// Precompute |emb_k|^2
__global__ void emb_norm_kernel(const float* __restrict__ emb, float* __restrict__ en, int K)
{
    const int k = blockIdx.x * TPB + threadIdx.x;
    if (k >= K) return;
    const float4* e = (const float4*)(emb + (size_t)k * 128);
    float s = 0.0f;
    for (int c = 0; c < 32; ++c) {
        const float4 t = e[c];
        s = fmaf(t.x, t.x, s); s = fmaf(t.y, t.y, s);
        s = fmaf(t.z, t.z, s); s = fmaf(t.w, t.w, s);
    }
    en[k] = s;
}

// ===========================================================================
// VQ (top, proven): 64 z-vectors per block; register tile 4v x 4e.
// ===========================================================================
#define VQ_TV 64
#define VQ_TE 64
__global__ __launch_bounds__(256) void vq_kernel(
    const float* __restrict__ z, const float* __restrict__ emb,
    const float* __restrict__ en_g,
    float* __restrict__ q, float* __restrict__ lossp,
    int HW, int Kc)
{
    __shared__ float zs[32][65][4];
    __shared__ float es[32][65][4];
    __shared__ float en[VQ_TE];
    __shared__ float rdd[VQ_TV][16];
    __shared__ int   rdi[VQ_TV][16];
    __shared__ int   idxv[VQ_TV];
    __shared__ float red[256];

    const int tid = threadIdx.x;
    const int vg = tid >> 4, eg = tid & 15;
    const long long gv0 = (long long)blockIdx.x * VQ_TV;
    const int n = (int)(gv0 / HW);
    const int p0 = (int)(gv0 - (long long)n * HW);
    const float* zb = z + (size_t)n * 128 * HW + p0;

    for (int i = tid; i < 64 * 128; i += 256) {
        const int v = i & 63, c = i >> 6;
        zs[c >> 2][v][c & 3] = zb[(size_t)c * HW + v];
    }
    __syncthreads();

    float best[4]; int bidx[4];
    #pragma unroll
    for (int r = 0; r < 4; ++r) { best[r] = 1e30f; bidx[r] = 0; }

    for (int e0 = 0; e0 < Kc; e0 += VQ_TE) {
        for (int i = tid; i < VQ_TE * 128; i += 256) {
            const int c = i & 127, el = i >> 7;
            es[c >> 2][el][c & 3] = emb[(size_t)(e0 + el) * 128 + c];
        }
        if (tid < VQ_TE) en[tid] = en_g[e0 + tid];
        __syncthreads();

        float dot[4][4];
        #pragma unroll
        for (int r = 0; r < 4; ++r)
            #pragma unroll
            for (int s = 0; s < 4; ++s) dot[r][s] = 0.0f;

        for (int c4 = 0; c4 < 32; ++c4) {
            float4 zr[4], ee[4];
            #pragma unroll
            for (int r = 0; r < 4; ++r) zr[r] = *(const float4*)&zs[c4][4 * vg + r][0];
            #pragma unroll
            for (int s = 0; s < 4; ++s) ee[s] = *(const float4*)&es[c4][eg + 16 * s][0];
            #pragma unroll
            for (int r = 0; r < 4; ++r) {
                #pragma unroll
                for (int s = 0; s < 4; ++s) {
                    dot[r][s] = fmaf(zr[r].x, ee[s].x, dot[r][s]);
                    dot[r][s] = fmaf(zr[r].y, ee[s].y, dot[r][s]);
                    dot[r][s] = fmaf(zr[r].z, ee[s].z, dot[r][s]);
                    dot[r][s] = fmaf(zr[r].w, ee[s].w, dot[r][s]);
                }
            }
        }
        #pragma unroll
        for (int s = 0; s < 4; ++s) {
            const float e2 = en[eg + 16 * s];
            const int ei = e0 + eg + 16 * s;
            #pragma unroll
            for (int r = 0; r < 4; ++r) {
                const float d = e2 - 2.0f * dot[r][s];
                if (d < best[r]) { best[r] = d; bidx[r] = ei; }
            }
        }
        __syncthreads();
    }

    #pragma unroll
    for (int r = 0; r < 4; ++r) { rdd[4 * vg + r][eg] = best[r]; rdi[4 * vg + r][eg] = bidx[r]; }
    __syncthreads();
    if (tid < VQ_TV) {
        float bd = rdd[tid][0]; int bi = rdi[tid][0];
        for (int j = 1; j < 16; ++j) {
            const float d = rdd[tid][j]; const int i2 = rdi[tid][j];
            if (d < bd || (d == bd && i2 < bi)) { bd = d; bi = i2; }
        }
        idxv[tid] = bi;
    }
    __syncthreads();

    float ls = 0.0f;
    float* qb = q + (size_t)n * 128 * HW + p0;
    for (int i = tid; i < 64 * 128; i += 256) {
        const int v = i & 63, c = i >> 6;
        const float e = emb[(size_t)idxv[v] * 128 + c];
        qb[(size_t)c * HW + v] = e;
        const float diff = e - zs[c >> 2][v][c & 3];
        ls = fmaf(diff, diff, ls);
    }
    red[tid] = ls;
    __syncthreads();
    for (int s = 128; s > 0; s >>= 1) {
        if (tid < s) red[tid] += red[tid + s];
        __syncthreads();
    }
    if (tid == 0) lossp[blockIdx.x] = red[0];
}

// ===========================================================================
// vq2 (bottom): 128 v x 128 e tile, 256 thr, thread = 8v x 8e.
// vg = tid>>4 (v = vg+16r), eg = tid&15 (e = eg+16s). Reads conflict-free;
// [129]-padded rows keep staging writes at 4-way. Same fmaf chain as vq_kernel
// -> bit-identical argmin. LDS ~134 KB, 1 block/CU, 4 waves.
// ===========================================================================
__global__ __launch_bounds__(256) void vq2_kernel(
    const float* __restrict__ z, const float* __restrict__ emb,
    const float* __restrict__ en_g,
    float* __restrict__ q, float* __restrict__ lossp,
    int HW, int Kc)
{
    __shared__ float zs[32][129][4];
    __shared__ float es[32][129][4];
    __shared__ float en[128];
    __shared__ int   idxv[128];
    __shared__ float red[256];

    const int tid = threadIdx.x;
    const int vg = tid >> 4, eg = tid & 15;
    const long long gv0 = (long long)blockIdx.x * 128;
    const int n = (int)(gv0 / HW);
    const int p0 = (int)(gv0 - (long long)n * HW);
    const float* zb = z + (size_t)n * 128 * HW + p0;

    // stage z: 128 c x 128 v, f4 over v (coalesced global reads)
    for (int i = tid; i < 128 * 32; i += 256) {
        const int c = i >> 5, v4 = i & 31;
        const float4 t = *(const float4*)(zb + (size_t)c * HW + 4 * v4);
        zs[c >> 2][4 * v4 + 0][c & 3] = t.x;
        zs[c >> 2][4 * v4 + 1][c & 3] = t.y;
        zs[c >> 2][4 * v4 + 2][c & 3] = t.z;
        zs[c >> 2][4 * v4 + 3][c & 3] = t.w;
    }
    __syncthreads();

    float best[8]; int bidx[8];
    #pragma unroll
    for (int r = 0; r < 8; ++r) { best[r] = 1e30f; bidx[r] = 0; }

    for (int e0 = 0; e0 < Kc; e0 += 128) {
        __syncthreads();
        for (int i = tid; i < 128 * 32; i += 256) {
            const int e = i >> 5, c4i = i & 31;          // coalesced global f4
            const float4 t = *(const float4*)(emb + (size_t)(e0 + e) * 128 + 4 * c4i);
            *(float4*)&es[c4i][e][0] = t;                // [129] pad -> 4-way
        }
        if (tid < 128) en[tid] = en_g[e0 + tid];
        __syncthreads();

        float dot[8][8];
        #pragma unroll
        for (int r = 0; r < 8; ++r)
            #pragma unroll
            for (int s = 0; s < 8; ++s) dot[r][s] = 0.0f;

        for (int c4 = 0; c4 < 32; ++c4) {
            float4 zr[8], ee[8];
            #pragma unroll
            for (int r = 0; r < 8; ++r) zr[r] = *(const float4*)&zs[c4][vg + 16 * r][0];
            #pragma unroll
            for (int s = 0; s < 8; ++s) ee[s] = *(const float4*)&es[c4][eg + 16 * s][0];
            #pragma unroll
            for (int r = 0; r < 8; ++r) {
                #pragma unroll
                for (int s = 0; s < 8; ++s) {
                    dot[r][s] = fmaf(zr[r].x, ee[s].x, dot[r][s]);
                    dot[r][s] = fmaf(zr[r].y, ee[s].y, dot[r][s]);
                    dot[r][s] = fmaf(zr[r].z, ee[s].z, dot[r][s]);
                    dot[r][s] = fmaf(zr[r].w, ee[s].w, dot[r][s]);
                }
            }
        }
        #pragma unroll
        for (int s = 0; s < 8; ++s) {
            const float e2 = en[eg + 16 * s];
            const int ei = e0 + eg + 16 * s;
            #pragma unroll
            for (int r = 0; r < 8; ++r) {
                const float d = e2 - 2.0f * dot[r][s];
                if (d < best[r]) { best[r] = d; bidx[r] = ei; }
            }
        }
    }

    // reduce over the 16 eg lanes (consecutive lanes within a wave)
    #pragma unroll
    for (int off = 8; off > 0; off >>= 1) {
        #pragma unroll
        for (int r = 0; r < 8; ++r) {
            const float d2 = __shfl_down(best[r], (unsigned)off, 16);
            const int   i2 = __shfl_down(bidx[r], (unsigned)off, 16);
            if (d2 < best[r] || (d2 == best[r] && i2 < bidx[r])) {
                best[r] = d2; bidx[r] = i2;
            }
        }
    }
    if (eg == 0) {
        #pragma unroll
        for (int r = 0; r < 8; ++r) idxv[vg + 16 * r] = bidx[r];
    }
    __syncthreads();

    // gather q + loss (coalesced q writes)
    float ls = 0.0f;
    float* qb = q + (size_t)n * 128 * HW + p0;
    for (int i = tid; i < 128 * 32; i += 256) {
        const int c = i >> 5, v4 = i & 31;
        float4 e4;
        e4.x = emb[(size_t)idxv[4 * v4 + 0] * 128 + c];
        e4.y = emb[(size_t)idxv[4 * v4 + 1] * 128 + c];
        e4.z = emb[(size_t)idxv[4 * v4 + 2] * 128 + c];
        e4.w = emb[(size_t)idxv[4 * v4 + 3] * 128 + c];
        *(float4*)(qb + (size_t)c * HW + 4 * v4) = e4;
        const float d0 = e4.x - zs[c >> 2][4 * v4 + 0][c & 3];
        const float d1 = e4.y - zs[c >> 2][4 * v4 + 1][c & 3];
        const float d2 = e4.z - zs[c >> 2][4 * v4 + 2][c & 3];
        const float d3 = e4.w - zs[c >> 2][4 * v4 + 3][c & 3];
        ls = fmaf(d0, d0, ls); ls = fmaf(d1, d1, ls);
        ls = fmaf(d2, d2, ls); ls = fmaf(d3, d3, ls);
    }
    red[tid] = ls;
    __syncthreads();
    for (int s = 128; s > 0; s >>= 1) {
        if (tid < s) red[tid] += red[tid + s];
        __syncthreads();
    }
    if (tid == 0) lossp[blockIdx.x] = red[0];
}

__global__ void loss_finish_kernel(const float* __restrict__ p, int n, float scale,
                                   float* __restrict__ out)
{
    __shared__ float red[256];
    float s = 0.0f;
    for (int i = threadIdx.x; i < n; i += 256) s += p[i];
    red[threadIdx.x] = s;
    __syncthreads();
    for (int k = 128; k > 0; k >>= 1) {
        if (threadIdx.x < k) red[threadIdx.x] += red[threadIdx.x + k];
        __syncthreads();
    }
    if (threadIdx.x == 0) out[0] = red[0] * scale;
}

// Final 1x1 heads (float4)
__global__ void outconv_kernel(const float* __restrict__ y,
                               const float* __restrict__ odw, const float* __restrict__ odb,
                               const float* __restrict__ orw, const float* __restrict__ orb,
                               float* __restrict__ out)
{
    const int idx = blockIdx.x * TPB + threadIdx.x;
    const int HW4 = 16384;
    if (idx >= 8 * 4 * HW4) return;
    const int p4 = idx & (HW4 - 1);
    const int t = idx >> 14;
    const int c = t & 3, n = t >> 2;
    const float4* yb4 = (const float4*)(y + (size_t)n * 32 * 65536);
    float4 v;
    const int base = (c == 0) ? 0 : 16;
    const float* wv = (c == 0) ? odw : orw + (c - 1) * 16;
    const float b = (c == 0) ? odb[0] : orb[c - 1];
    v.x = b; v.y = b; v.z = b; v.w = b;
    for (int k = 0; k < 16; ++k) {
        const float w = wv[k];
        const float4 f = yb4[(size_t)(base + k) * HW4 + p4];
        v.x = fmaf(f.x, w, v.x); v.y = fmaf(f.y, w, v.y);
        v.z = fmaf(f.z, w, v.z); v.w = fmaf(f.w, w, v.w);
    }
    ((float4*)out)[idx] = v;
}

extern "C" void kernel_launch(void* const* d_in, const int* in_sizes, int n_in,
                              void* d_out, int out_size, void* d_ws, size_t ws_size,
                              hipStream_t stream)
{
    const float* x      = (const float*)d_in[0];
    const float* eb_dw  = (const float*)d_in[1];
    const float* eb_db  = (const float*)d_in[2];
    const float* eb_rw  = (const float*)d_in[3];
    const float* eb_rb  = (const float*)d_in[4];
    const float* eb_c1w = (const float*)d_in[5];
    const float* eb_c1b = (const float*)d_in[6];
    const float* eb_c2w = (const float*)d_in[7];
    const float* eb_c2b = (const float*)d_in[8];
    const float* eb_c3w = (const float*)d_in[9];
    const float* eb_c3b = (const float*)d_in[10];
    const float* eb_rw1 = (const float*)d_in[11];
    const float* eb_rw2 = (const float*)d_in[12];
    const float* et_c1w = (const float*)d_in[13];
    const float* et_c1b = (const float*)d_in[14];
    const float* et_c2w = (const float*)d_in[15];
    const float* et_c2b = (const float*)d_in[16];
    const float* et_rw1 = (const float*)d_in[17];
    const float* et_rw2 = (const float*)d_in[18];
    const float* pvt_w  = (const float*)d_in[19];
    const float* pvt_b  = (const float*)d_in[20];
    const float* up_w   = (const float*)d_in[21];
    const float* up_b   = (const float*)d_in[22];
    const float* pvb_w  = (const float*)d_in[23];
    const float* pvb_b  = (const float*)d_in[24];
    const float* emb_t  = (const float*)d_in[25];
    const float* emb_b  = (const float*)d_in[26];
    const float* db_c1w = (const float*)d_in[27];
    const float* db_c1b = (const float*)d_in[28];
    const float* db_rw1 = (const float*)d_in[29];
    const float* db_rw2 = (const float*)d_in[30];
    const float* db_t1w = (const float*)d_in[31];
    const float* db_t1b = (const float*)d_in[32];
    const float* db_t2w = (const float*)d_in[33];
    const float* db_t2b = (const float*)d_in[34];
    const float* db_odw = (const float*)d_in[35];
    const float* db_odb = (const float*)d_in[36];
    const float* db_orw = (const float*)d_in[37];
    const float* db_orb = (const float*)d_in[38];

    float* ws  = (float*)d_ws;
    float* out = (float*)d_out;

    // ---- workspace arena (float offsets). Round-4 live-range proof.
    const size_t OFF_H0   = 0;
    const size_t OFF_H1   = 33554432;
    const size_t OFF_H2   = 0;
    const size_t OFF_ENCB = 4194304;
    const size_t OFF_RH   = 8388608;
    const size_t OFF_T1   = 10485760;
    const size_t OFF_T2   = 11534336;
    const size_t OFF_ZT   = 12582912;
    const size_t OFF_UPT  = 13631488;
    const size_t OFF_ZB   = 17825792;
    const size_t OFF_Y    = 22020096;
    const size_t OFF_Y1   = 26214400;
    const size_t OFF_Y2   = 0;
    const size_t OFF_ENT  = 34603008;
    const size_t OFF_ENB  = 34605056;
    const size_t OFF_LPT  = 34607104;
    const size_t OFF_LPB  = 34607232;
    const size_t NEED     = 41943680;
    if (ws_size < NEED * sizeof(float)) return;

    // ---- output layout: loss_b, loss_t, recon, q_t, q_b ----
    float* o_loss_b = out + 0;
    float* o_loss_t = out + 1;
    float* o_recon  = out + 2;
    float* o_qt     = out + 2 + 8 * 4 * 65536;
    float* o_qb     = o_qt + 8 * 128 * 1024;

    // ===== EncoderBot =====
    head_kernel<<<8 * 64 * 16384 / TPB, TPB, 0, stream>>>(
        x, eb_dw, eb_db, eb_rw, eb_rb, ws + OFF_H0);
    conv4s2_kernel<128, 2><<<dim3(64, 2, 8), 256, 0, stream>>>(
        ws + OFF_H0, eb_c1w, eb_c1b, ws + OFF_H1, 64, 64, 1);
    conv4s2_kernel<64, 4><<<dim3(16, 4, 8), 256, 0, stream>>>(
        ws + OFF_H1, eb_c2w, eb_c2b, ws + OFF_H2, 64, 128, 1);
    emb_norm_kernel<<<8, TPB, 0, stream>>>(emb_t, ws + OFF_ENT, 2048);
    emb_norm_kernel<<<8, TPB, 0, stream>>>(emb_b, ws + OFF_ENB, 2048);
    conv3_kernel<64, 4, 16, false, false><<<dim3(16, 2, 8), 256, 0, stream>>>(
        ws + OFF_H2, nullptr, eb_c3w, eb_c3b, ws + OFF_ENCB, 128, 128, 0);
    for (int i = 0; i < 2; ++i) {
        conv3_kernel<64, 4, 8, true, false><<<dim3(16, 2, 8), 256, 0, stream>>>(
            ws + OFF_ENCB, nullptr, eb_rw1 + (size_t)i * 64 * 64 * 9, nullptr,
            ws + OFF_RH, 128, 64, 0);
        if (i == 1)
            conv1_kernel<256, true, true, true, false><<<dim3(16, 4, 8), 256, 0, stream>>>(
                ws + OFF_RH, nullptr, eb_rw2 + (size_t)i * 128 * 32, nullptr,
                ws + OFF_ENCB, 64, 128, 4096);
        else
            conv1_kernel<256, true, true, false, false><<<dim3(16, 4, 8), 256, 0, stream>>>(
                ws + OFF_RH, nullptr, eb_rw2 + (size_t)i * 128 * 32, nullptr,
                ws + OFF_ENCB, 64, 128, 4096);
    }

    // ===== EncoderTop =====
    conv4s2_kernel<32, 4><<<dim3(8, 4, 8), 256, 0, stream>>>(
        ws + OFF_ENCB, et_c1w, et_c1b, ws + OFF_T1, 128, 128, 1);
    conv3_kernel<32, 4, 8, false, false><<<dim3(8, 4, 8), 256, 0, stream>>>(
        ws + OFF_T1, nullptr, et_c2w, et_c2b, ws + OFF_T2, 128, 128, 1);
    for (int i = 0; i < 2; ++i) {
        conv3_kernel<32, 4, 4, true, false><<<dim3(8, 4, 8), 256, 0, stream>>>(
            ws + OFF_T2, nullptr, et_rw1 + (size_t)i * 64 * 64 * 9, nullptr,
            ws + OFF_RH, 128, 64, 0);
        if (i == 1)
            conv1_kernel<128, true, true, true, false><<<dim3(8, 4, 8), 256, 0, stream>>>(
                ws + OFF_RH, nullptr, et_rw2 + (size_t)i * 128 * 32, nullptr,
                ws + OFF_T2, 64, 128, 1024);
        else
            conv1_kernel<128, true, true, false, false><<<dim3(8, 4, 8), 256, 0, stream>>>(
                ws + OFF_RH, nullptr, et_rw2 + (size_t)i * 128 * 32, nullptr,
                ws + OFF_T2, 64, 128, 1024);
    }

    // ===== top VQ (proven 64x64 kernel) =====
    conv1_kernel<128, false, false, false, false><<<dim3(8, 4, 8), 256, 0, stream>>>(
        ws + OFF_T2, nullptr, pvt_w, pvt_b, ws + OFF_ZT, 128, 128, 1024);
    vq_kernel<<<128, 256, 0, stream>>>(ws + OFF_ZT, emb_t, ws + OFF_ENT, o_qt,
                                       ws + OFF_LPT, 1024, 2048);
    loss_finish_kernel<<<1, 256, 0, stream>>>(ws + OFF_LPT, 128,
                                              0.25f / (8192.0f * 128.0f), o_loss_t);

    convt4_kernel<64, 4, 32><<<dim3(16, 4, 8), 256, 0, stream>>>(
        o_qt, up_w, up_b, ws + OFF_UPT, 128, 128, 0);

    // ===== PreVQBot / bottom VQ (new 128x128 kernel) =====
    conv1_kernel<256, false, false, false, true><<<dim3(16, 4, 8), 256, 0, stream>>>(
        ws + OFF_ENCB, ws + OFF_UPT, pvb_w, pvb_b, ws + OFF_ZB, 256, 128, 4096);
    vq2_kernel<<<256, 256, 0, stream>>>(ws + OFF_ZB, emb_b, ws + OFF_ENB, o_qb,
                                        ws + OFF_LPB, 4096, 2048);
    loss_finish_kernel<<<1, 256, 0, stream>>>(ws + OFF_LPB, 256,
                                              0.25f / (32768.0f * 128.0f), o_loss_b);

    // ===== DecoderBot =====
    conv3_kernel<64, 4, 16, false, true><<<dim3(16, 2, 8), 256, 0, stream>>>(
        ws + OFF_UPT, o_qb, db_c1w, db_c1b, ws + OFF_Y, 256, 128, 0);
    for (int i = 0; i < 2; ++i) {
        conv3_kernel<64, 4, 8, true, false><<<dim3(16, 2, 8), 256, 0, stream>>>(
            ws + OFF_Y, nullptr, db_rw1 + (size_t)i * 64 * 64 * 9, nullptr,
            ws + OFF_RH, 128, 64, 0);
        if (i == 1)
            conv1_kernel<256, true, true, true, false><<<dim3(16, 4, 8), 256, 0, stream>>>(
                ws + OFF_RH, nullptr, db_rw2 + (size_t)i * 128 * 32, nullptr,
                ws + OFF_Y, 64, 128, 4096);
        else
            conv1_kernel<256, true, true, false, false><<<dim3(16, 4, 8), 256, 0, stream>>>(
                ws + OFF_RH, nullptr, db_rw2 + (size_t)i * 128 * 32, nullptr,
                ws + OFF_Y, 64, 128, 4096);
    }
    convt4_kernel<128, 2, 32><<<dim3(64, 2, 8), 256, 0, stream>>>(
        ws + OFF_Y, db_t1w, db_t1b, ws + OFF_Y1, 128, 64, 1);
    convt4_kernel<256, 2, 16><<<dim3(128, 2, 8), 128, 0, stream>>>(
        ws + OFF_Y1, db_t2w, db_t2b, ws + OFF_Y2, 64, 32, 0);
    outconv_kernel<<<8 * 4 * 16384 / TPB, TPB, 0, stream>>>(
        ws + OFF_Y2, db_odw, db_odb, db_orw, db_orb, o_recon);
}

// Round 14
// 1761.306 us; speedup vs baseline: 1.0667x; 1.0667x over previous
//
#include <hip/hip_runtime.h>
#include <cstddef>

#define TPB 256

__device__ __forceinline__ float4 relu4(float4 v) {
    v.x = fmaxf(v.x, 0.0f); v.y = fmaxf(v.y, 0.0f);
    v.z = fmaxf(v.z, 0.0f); v.w = fmaxf(v.w, 0.0f);
    return v;
}

// joined ch (g*128 + l): l<64 -> a[n][g*64+l], else b[n][g*64+l-64]
__device__ __forceinline__ const float* pick_src(const float* a, const float* b,
                                                 int n, int g, int l, int HW) {
    return (l < 64) ? a + ((size_t)n * 128 + g * 64 + l) * HW
                    : b + ((size_t)n * 128 + g * 64 + (l - 64)) * HW;
}

// ===========================================================================
// 3x3 s1 p1 grouped conv (groups=2). Tile: (4*OCB) oc x (ROWS*W) px. 256 thr.
// Each thread: OCB oc x J px (strided px -> conflict-free b32 LDS reads).
// ===========================================================================
template<int W, int ROWS, int OCB, bool RELU_IN, bool SPLIT>
__global__ __launch_bounds__(256) void conv3_kernel(
    const float* __restrict__ in, const float* __restrict__ in2,
    const float* __restrict__ wgt, const float* __restrict__ bias,
    float* __restrict__ out, int Cin, int Cout, int relu_out)
{
    constexpr int J = ROWS * W / 64;
    constexpr int OCT = OCB * 4;
    constexpr int NW = OCB / 4;
    constexpr int ICB = 8;
    constexpr int IN_H = ROWS + 2, IN_W2 = W + 8;
    constexpr int W4 = W / 4;
    __shared__ float s_in[ICB][IN_H][IN_W2];
    __shared__ float s_w[ICB * 9 * OCT];

    const int tid = threadIdx.x;
    const int tx = tid & 63, ty = tid >> 6;
    const int n = blockIdx.z, oc0 = blockIdx.y * OCT, r0 = blockIdx.x * ROWS;
    const int icg = Cin >> 1, ocg = Cout >> 1;
    const int g = oc0 / ocg;

    float acc[OCB][J];
    #pragma unroll
    for (int o = 0; o < OCB; ++o) {
        const float b = bias ? bias[oc0 + ty * OCB + o] : 0.0f;
        #pragma unroll
        for (int j = 0; j < J; ++j) acc[o][j] = b;
    }

    const float* inb = SPLIT ? nullptr
                             : in + ((size_t)n * Cin + (size_t)g * icg) * (W * W);

    for (int ic0 = 0; ic0 < icg; ic0 += ICB) {
        __syncthreads();
        for (int i = tid; i < ICB * IN_H * W4; i += 256) {
            const int icl = i / (IN_H * W4);
            const int rem = i - icl * (IN_H * W4);
            const int rr = rem / W4, c4 = rem - rr * W4;
            const int y = r0 - 1 + rr;
            float4 v = make_float4(0.f, 0.f, 0.f, 0.f);
            if ((unsigned)y < (unsigned)W) {
                const float* src = SPLIT ? pick_src(in, in2, n, g, ic0 + icl, W * W)
                                         : inb + (size_t)(ic0 + icl) * (W * W);
                v = *(const float4*)(src + (size_t)y * W + 4 * c4);
            }
            if (RELU_IN) v = relu4(v);
            *(float4*)&s_in[icl][rr][4 + 4 * c4] = v;
        }
        for (int i = tid; i < ICB * IN_H; i += 256) {
            const int icl = i / IN_H, rr = i - icl * IN_H;
            s_in[icl][rr][3] = 0.0f;
            s_in[icl][rr][W + 4] = 0.0f;
        }
        for (int i = tid; i < ICB * 9 * OCT; i += 256) {
            const int ocl = i % OCT, rest = i / OCT;
            const int k = rest % 9, icl = rest / 9;
            s_w[i] = wgt[((size_t)(oc0 + ocl) * icg + (ic0 + icl)) * 9 + k];
        }
        __syncthreads();

        #pragma unroll 1
        for (int icl = 0; icl < ICB; ++icl) {
            const float* swb = s_w + icl * 9 * OCT + ty * OCB;
            #pragma unroll
            for (int ky = 0; ky < 3; ++ky) {
                #pragma unroll
                for (int kx = 0; kx < 3; ++kx) {
                    const int kq = ky * 3 + kx;
                    float4 wv[NW];
                    #pragma unroll
                    for (int u = 0; u < NW; ++u)
                        wv[u] = *(const float4*)(swb + kq * OCT + 4 * u);
                    #pragma unroll
                    for (int j = 0; j < J; ++j) {
                        const int p = j * 64 + tx;
                        const int rr = p / W, cc = p - rr * W;
                        const float v = s_in[icl][rr + ky][cc + 3 + kx];
                        #pragma unroll
                        for (int u = 0; u < NW; ++u) {
                            acc[4 * u + 0][j] = fmaf(wv[u].x, v, acc[4 * u + 0][j]);
                            acc[4 * u + 1][j] = fmaf(wv[u].y, v, acc[4 * u + 1][j]);
                            acc[4 * u + 2][j] = fmaf(wv[u].z, v, acc[4 * u + 2][j]);
                            acc[4 * u + 3][j] = fmaf(wv[u].w, v, acc[4 * u + 3][j]);
                        }
                    }
                }
            }
        }
    }

    const int HWo = W * W;
    float* ob = out + ((size_t)n * Cout + oc0 + ty * OCB) * HWo;
    #pragma unroll
    for (int o = 0; o < OCB; ++o) {
        #pragma unroll
        for (int j = 0; j < J; ++j) {
            const int p = j * 64 + tx;
            const int rr = p / W, cc = p - rr * W;
            float r = acc[o][j];
            if (relu_out) r = fmaxf(r, 0.0f);
            ob[(size_t)o * HWo + (size_t)(r0 + rr) * W + cc] = r;
        }
    }
}

// ===========================================================================
// 4x4 s2 p1 grouped conv (groups=2). W = OUTPUT width; input 2W x 2W.
// ===========================================================================
template<int W, int ROWS>
__global__ __launch_bounds__(256) void conv4s2_kernel(
    const float* __restrict__ in, const float* __restrict__ wgt,
    const float* __restrict__ bias, float* __restrict__ out,
    int Cin, int Cout, int relu_out)
{
    constexpr int J = ROWS * W / 64;
    constexpr int ICB = 4;
    constexpr int IN_H = 2 * ROWS + 2, IN_W2 = 2 * W + 8;
    constexpr int W24 = W / 2;
    __shared__ float s_in[ICB][IN_H][IN_W2];
    __shared__ float s_w[ICB * 16 * 32];

    const int tid = threadIdx.x;
    const int tx = tid & 63, ty = tid >> 6;
    const int n = blockIdx.z, oc0 = blockIdx.y * 32, r0 = blockIdx.x * ROWS;
    const int icg = Cin >> 1, ocg = Cout >> 1;
    const int g = oc0 / ocg;
    const int Hin = 2 * W;

    float acc[8][J];
    #pragma unroll
    for (int o = 0; o < 8; ++o) {
        const float b = bias ? bias[oc0 + ty * 8 + o] : 0.0f;
        #pragma unroll
        for (int j = 0; j < J; ++j) acc[o][j] = b;
    }

    const float* inb = in + ((size_t)n * Cin + (size_t)g * icg) * (Hin * Hin);
    for (int ic0 = 0; ic0 < icg; ic0 += ICB) {
        __syncthreads();
        for (int i = tid; i < ICB * IN_H * W24; i += 256) {
            const int icl = i / (IN_H * W24);
            const int rem = i - icl * (IN_H * W24);
            const int rr = rem / W24, c4 = rem - rr * W24;
            const int y = 2 * r0 - 1 + rr;
            float4 v = make_float4(0.f, 0.f, 0.f, 0.f);
            if ((unsigned)y < (unsigned)Hin)
                v = *(const float4*)(inb + (size_t)(ic0 + icl) * (Hin * Hin)
                                     + (size_t)y * Hin + 4 * c4);
            *(float4*)&s_in[icl][rr][4 + 4 * c4] = v;
        }
        for (int i = tid; i < ICB * IN_H; i += 256) {
            const int icl = i / IN_H, rr = i - icl * IN_H;
            s_in[icl][rr][3] = 0.0f;
            s_in[icl][rr][2 * W + 4] = 0.0f;
        }
        for (int i = tid; i < ICB * 16 * 32; i += 256) {
            const int ocl = i & 31, rest = i >> 5;
            const int k = rest & 15, icl = rest >> 4;
            s_w[i] = wgt[((size_t)(oc0 + ocl) * icg + (ic0 + icl)) * 16 + k];
        }
        __syncthreads();

        #pragma unroll 1
        for (int icl = 0; icl < ICB; ++icl) {
            const float* swb = s_w + icl * 512 + ty * 8;
            #pragma unroll
            for (int ky = 0; ky < 4; ++ky) {
                #pragma unroll
                for (int kx = 0; kx < 4; ++kx) {
                    const int kq = ky * 4 + kx;
                    const float4 wA = *(const float4*)(swb + kq * 32);
                    const float4 wB = *(const float4*)(swb + kq * 32 + 4);
                    #pragma unroll
                    for (int j = 0; j < J; ++j) {
                        const int p = j * 64 + tx;
                        const int rr = p / W, cc = p - rr * W;
                        const float v = s_in[icl][2 * rr + ky][2 * cc + 3 + kx];
                        acc[0][j] = fmaf(wA.x, v, acc[0][j]);
                        acc[1][j] = fmaf(wA.y, v, acc[1][j]);
                        acc[2][j] = fmaf(wA.z, v, acc[2][j]);
                        acc[3][j] = fmaf(wA.w, v, acc[3][j]);
                        acc[4][j] = fmaf(wB.x, v, acc[4][j]);
                        acc[5][j] = fmaf(wB.y, v, acc[5][j]);
                        acc[6][j] = fmaf(wB.z, v, acc[6][j]);
                        acc[7][j] = fmaf(wB.w, v, acc[7][j]);
                    }
                }
            }
        }
    }

    const int HWo = W * W;
    float* ob = out + ((size_t)n * Cout + oc0 + ty * 8) * HWo;
    #pragma unroll
    for (int o = 0; o < 8; ++o) {
        #pragma unroll
        for (int j = 0; j < J; ++j) {
            const int p = j * 64 + tx;
            const int rr = p / W, cc = p - rr * W;
            float r = acc[o][j];
            if (relu_out) r = fmaxf(r, 0.0f);
            ob[(size_t)o * HWo + (size_t)(r0 + rr) * W + cc] = r;
        }
    }
}

// ===========================================================================
// 1x1 grouped conv (pixel GEMM). Tile: 32 oc x PX px.
// ===========================================================================
template<int PX, bool RELU_IN, bool ACC, bool RELU_OUT, bool SPLIT>
__global__ __launch_bounds__(256) void conv1_kernel(
    const float* __restrict__ in, const float* __restrict__ in2,
    const float* __restrict__ wgt, const float* __restrict__ bias,
    float* __restrict__ out, int Cin, int Cout, int HW)
{
    constexpr int J = PX / 64;
    constexpr int PX4 = PX / 4;
    constexpr int ICB = 16;
    __shared__ float s_in[ICB][PX];
    __shared__ float s_w[ICB * 32];

    const int tid = threadIdx.x;
    const int tx = tid & 63, ty = tid >> 6;
    const int n = blockIdx.z, oc0 = blockIdx.y * 32, p0 = blockIdx.x * PX;
    const int icg = Cin >> 1, ocg = Cout >> 1;
    const int g = oc0 / ocg;

    float acc[8][J];
    #pragma unroll
    for (int o = 0; o < 8; ++o) {
        const float b = bias ? bias[oc0 + ty * 8 + o] : 0.0f;
        #pragma unroll
        for (int j = 0; j < J; ++j) acc[o][j] = b;
    }

    const float* inb = SPLIT ? nullptr
                             : in + ((size_t)n * Cin + (size_t)g * icg) * HW + p0;
    for (int ic0 = 0; ic0 < icg; ic0 += ICB) {
        __syncthreads();
        for (int i = tid; i < ICB * PX4; i += 256) {
            const int icl = i / PX4, c4 = i - (i / PX4) * PX4;
            const float* src = SPLIT ? pick_src(in, in2, n, g, ic0 + icl, HW) + p0
                                     : inb + (size_t)(ic0 + icl) * HW;
            float4 v = *(const float4*)(src + 4 * c4);
            if (RELU_IN) v = relu4(v);
            *(float4*)&s_in[icl][4 * c4] = v;
        }
        for (int i = tid; i < ICB * 32; i += 256) {
            const int ocl = i & 31, icl = i >> 5;
            s_w[i] = wgt[(size_t)(oc0 + ocl) * icg + ic0 + icl];
        }
        __syncthreads();

        #pragma unroll 4
        for (int icl = 0; icl < ICB; ++icl) {
            const float4 wA = *(const float4*)(s_w + icl * 32 + ty * 8);
            const float4 wB = *(const float4*)(s_w + icl * 32 + ty * 8 + 4);
            #pragma unroll
            for (int j = 0; j < J; ++j) {
                const float v = s_in[icl][j * 64 + tx];
                acc[0][j] = fmaf(wA.x, v, acc[0][j]);
                acc[1][j] = fmaf(wA.y, v, acc[1][j]);
                acc[2][j] = fmaf(wA.z, v, acc[2][j]);
                acc[3][j] = fmaf(wA.w, v, acc[3][j]);
                acc[4][j] = fmaf(wB.x, v, acc[4][j]);
                acc[5][j] = fmaf(wB.y, v, acc[5][j]);
                acc[6][j] = fmaf(wB.z, v, acc[6][j]);
                acc[7][j] = fmaf(wB.w, v, acc[7][j]);
            }
        }
    }

    float* ob = out + ((size_t)n * Cout + oc0 + ty * 8) * HW + p0;
    #pragma unroll
    for (int o = 0; o < 8; ++o) {
        #pragma unroll
        for (int j = 0; j < J; ++j) {
            const size_t idx = (size_t)o * HW + j * 64 + tx;
            float r = acc[o][j];
            if (ACC) r += ob[idx];
            if (RELU_OUT) r = fmaxf(r, 0.0f);
            ob[idx] = r;
        }
    }
}

// ===========================================================================
// Grouped ConvTranspose2d K4 s2 p1 (groups=2). W = OUTPUT width; input W/2.
// torch layout w: (Cin, Cout/groups, 4, 4). Parity-decomposed taps.
// ===========================================================================
template<int W, int ROWS, int OCT>
__global__ __launch_bounds__(64 * (OCT / 8)) void convt4_kernel(
    const float* __restrict__ in, const float* __restrict__ wgt,
    const float* __restrict__ bias, float* __restrict__ out,
    int Cin, int Cout, int relu_out)
{
    constexpr int NTHR = 64 * (OCT / 8);
    constexpr int PXT  = ROWS * W / 64;
    constexpr int WP   = W / 64;
    constexpr int ICB  = 8;
    constexpr int RIN  = ((ROWS + 1) >> 1) + 2;
    constexpr int CIN  = W / 2 + 2;
    __shared__ float s_in[ICB][RIN][CIN];
    __shared__ float s_w[ICB * 16 * OCT];

    const int tid = threadIdx.x;
    const int tx = tid & 63, ty = tid >> 6;
    const int n = blockIdx.z;
    const int oc0 = blockIdx.y * OCT;
    const int r0 = blockIdx.x * ROWS;
    const int icg = Cin >> 1, ocg = Cout >> 1;
    const int g = oc0 / ocg, of0 = oc0 - g * ocg;
    const int Hin = W / 2;
    const int iy_lo = (r0 - 2) >> 1;

    float acc[8][PXT];
    #pragma unroll
    for (int o = 0; o < 8; ++o) {
        const float b = bias ? bias[oc0 + ty * 8 + o] : 0.0f;
        #pragma unroll
        for (int j = 0; j < PXT; ++j) acc[o][j] = b;
    }

    const float* inb = in + ((size_t)n * Cin + (size_t)g * icg) * (Hin * Hin);
    const int kxl = ((tx + 1) & 1);
    const int hx  = (tx + 1) >> 1;

    for (int ic0 = 0; ic0 < icg; ic0 += ICB) {
        __syncthreads();
        for (int i = tid; i < ICB * RIN * CIN; i += NTHR) {
            const int icl = i / (RIN * CIN);
            const int rem = i - icl * (RIN * CIN);
            const int rr = rem / CIN, cc = rem - rr * CIN;
            const int y = iy_lo + rr, x = cc - 1;
            float v = 0.0f;
            if ((unsigned)y < (unsigned)Hin && (unsigned)x < (unsigned)Hin)
                v = inb[(size_t)(ic0 + icl) * (Hin * Hin) + y * Hin + x];
            s_in[icl][rr][cc] = v;
        }
        for (int i = tid; i < ICB * 16 * OCT; i += NTHR) {
            const int ocl = i & (OCT - 1);
            const int rest = i / OCT;
            const int k = rest & 15, icl = rest >> 4;
            s_w[i] = wgt[((size_t)(g * icg + ic0 + icl) * ocg + of0 + ocl) * 16 + k];
        }
        __syncthreads();

        #pragma unroll 1
        for (int icl = 0; icl < ICB; ++icl) {
            const float* swb = s_w + icl * 16 * OCT + ty * 8;
            #pragma unroll
            for (int tt = 0; tt < 4; ++tt) {
                const int ty2 = tt >> 1, tx2 = tt & 1;
                float4 wp0[2], wp1[2];
                #pragma unroll
                for (int par = 0; par < 2; ++par) {
                    const int koff = ((2 * ty2 + par) * 4 + (kxl + 2 * tx2)) * OCT;
                    wp0[par] = *(const float4*)(swb + koff);
                    wp1[par] = *(const float4*)(swb + koff + 4);
                }
                const int cbase = hx - tx2 + 1;
                #pragma unroll
                for (int j = 0; j < PXT; ++j) {
                    const int row_j = j / WP, m_j = j - row_j * WP;
                    const int pj = (row_j + 1) & 1;
                    const int rloc = (row_j + 1 - pj) / 2 - ty2 + 1;
                    const float v = s_in[icl][rloc][32 * m_j + cbase];
                    const float4 wa = pj ? wp0[1] : wp0[0];
                    const float4 wb = pj ? wp1[1] : wp1[0];
                    acc[0][j] = fmaf(wa.x, v, acc[0][j]);
                    acc[1][j] = fmaf(wa.y, v, acc[1][j]);
                    acc[2][j] = fmaf(wa.z, v, acc[2][j]);
                    acc[3][j] = fmaf(wa.w, v, acc[3][j]);
                    acc[4][j] = fmaf(wb.x, v, acc[4][j]);
                    acc[5][j] = fmaf(wb.y, v, acc[5][j]);
                    acc[6][j] = fmaf(wb.z, v, acc[6][j]);
                    acc[7][j] = fmaf(wb.w, v, acc[7][j]);
                }
            }
        }
    }

    const int HWo = W * W;
    float* ob = out + ((size_t)n * Cout + oc0 + ty * 8) * HWo;
    #pragma unroll
    for (int o = 0; o < 8; ++o) {
        #pragma unroll
        for (int j = 0; j < PXT; ++j) {
            const int row_j = j / WP, m_j = j - row_j * WP;
            float r = acc[o][j];
            if (relu_out) r = fmaxf(r, 0.0f);
            ob[(size_t)o * HWo + (size_t)(r0 + row_j) * W + 64 * m_j + tx] = r;
        }
    }
}

// ===========================================================================
// Fused encoder head (float4)
// ===========================================================================
__global__ void head_kernel(const float* __restrict__ x,
                            const float* __restrict__ dw, const float* __restrict__ db,
                            const float* __restrict__ rw, const float* __restrict__ rb,
                            float* __restrict__ out)
{
    const int idx = blockIdx.x * TPB + threadIdx.x;
    const int HW4 = 16384;
    if (idx >= 8 * 64 * HW4) return;
    const int p4 = idx & (HW4 - 1);
    const int t = idx >> 14;
    const int c = t & 63, n = t >> 6;
    const float4* xb4 = (const float4*)(x + (size_t)n * 4 * 65536);
    float4 v;
    if (c < 32) {
        const float w = dw[c], b = db[c];
        const float4 d = xb4[p4];
        v.x = fmaf(d.x, w, b); v.y = fmaf(d.y, w, b);
        v.z = fmaf(d.z, w, b); v.w = fmaf(d.w, w, b);
    } else {
        const int cc = c - 32;
        const float w0 = rw[cc * 3], w1 = rw[cc * 3 + 1], w2 = rw[cc * 3 + 2];
        const float b = rb[cc];
        const float4 r = xb4[HW4 + p4], g4 = xb4[2 * HW4 + p4], bl = xb4[3 * HW4 + p4];
        v.x = fmaf(bl.x, w2, fmaf(g4.x, w1, fmaf(r.x, w0, b)));
        v.y = fmaf(bl.y, w2, fmaf(g4.y, w1, fmaf(r.y, w0, b)));
        v.z = fmaf(bl.z, w2, fmaf(g4.z, w1, fmaf(r.z, w0, b)));
        v.w = fmaf(bl.w, w2, fmaf(g4.w, w1, fmaf(r.w, w0, b)));
    }
    ((float4*)out)[idx] = relu4(v);
}

// Precompute |emb_k|^2
__global__ void emb_norm_kernel(const float* __restrict__ emb, float* __restrict__ en, int K)
{
    const int k = blockIdx.x * TPB + threadIdx.x;
    if (k >= K) return;
    const float4* e = (const float4*)(emb + (size_t)k * 128);
    float s = 0.0f;
    for (int c = 0; c < 32; ++c) {
        const float4 t = e[c];
        s = fmaf(t.x, t.x, s); s = fmaf(t.y, t.y, s);
        s = fmaf(t.z, t.z, s); s = fmaf(t.w, t.w, s);
    }
    en[k] = s;
}

// ===========================================================================
// VQ: 64 z-vectors per block; register tile 4v x 4e; float4 c-chunks in LDS.
// ===========================================================================
#define VQ_TV 64
#define VQ_TE 64
__global__ __launch_bounds__(256) void vq_kernel(
    const float* __restrict__ z, const float* __restrict__ emb,
    const float* __restrict__ en_g,
    float* __restrict__ q, float* __restrict__ lossp,
    int HW, int Kc)
{
    __shared__ float zs[32][65][4];
    __shared__ float es[32][65][4];
    __shared__ float en[VQ_TE];
    __shared__ float rdd[VQ_TV][16];
    __shared__ int   rdi[VQ_TV][16];
    __shared__ int   idxv[VQ_TV];
    __shared__ float red[256];

    const int tid = threadIdx.x;
    const int vg = tid >> 4, eg = tid & 15;
    const long long gv0 = (long long)blockIdx.x * VQ_TV;
    const int n = (int)(gv0 / HW);
    const int p0 = (int)(gv0 - (long long)n * HW);
    const float* zb = z + (size_t)n * 128 * HW + p0;

    for (int i = tid; i < 64 * 128; i += 256) {
        const int v = i & 63, c = i >> 6;
        zs[c >> 2][v][c & 3] = zb[(size_t)c * HW + v];
    }
    __syncthreads();

    float best[4]; int bidx[4];
    #pragma unroll
    for (int r = 0; r < 4; ++r) { best[r] = 1e30f; bidx[r] = 0; }

    for (int e0 = 0; e0 < Kc; e0 += VQ_TE) {
        for (int i = tid; i < VQ_TE * 128; i += 256) {
            const int c = i & 127, el = i >> 7;
            es[c >> 2][el][c & 3] = emb[(size_t)(e0 + el) * 128 + c];
        }
        if (tid < VQ_TE) en[tid] = en_g[e0 + tid];
        __syncthreads();

        float dot[4][4];
        #pragma unroll
        for (int r = 0; r < 4; ++r)
            #pragma unroll
            for (int s = 0; s < 4; ++s) dot[r][s] = 0.0f;

        for (int c4 = 0; c4 < 32; ++c4) {
            float4 zr[4], ee[4];
            #pragma unroll
            for (int r = 0; r < 4; ++r) zr[r] = *(const float4*)&zs[c4][4 * vg + r][0];
            #pragma unroll
            for (int s = 0; s < 4; ++s) ee[s] = *(const float4*)&es[c4][eg + 16 * s][0];
            #pragma unroll
            for (int r = 0; r < 4; ++r) {
                #pragma unroll
                for (int s = 0; s < 4; ++s) {
                    dot[r][s] = fmaf(zr[r].x, ee[s].x, dot[r][s]);
                    dot[r][s] = fmaf(zr[r].y, ee[s].y, dot[r][s]);
                    dot[r][s] = fmaf(zr[r].z, ee[s].z, dot[r][s]);
                    dot[r][s] = fmaf(zr[r].w, ee[s].w, dot[r][s]);
                }
            }
        }
        #pragma unroll
        for (int s = 0; s < 4; ++s) {
            const float e2 = en[eg + 16 * s];
            const int ei = e0 + eg + 16 * s;
            #pragma unroll
            for (int r = 0; r < 4; ++r) {
                const float d = e2 - 2.0f * dot[r][s];
                if (d < best[r]) { best[r] = d; bidx[r] = ei; }
            }
        }
        __syncthreads();
    }

    #pragma unroll
    for (int r = 0; r < 4; ++r) { rdd[4 * vg + r][eg] = best[r]; rdi[4 * vg + r][eg] = bidx[r]; }
    __syncthreads();
    if (tid < VQ_TV) {
        float bd = rdd[tid][0]; int bi = rdi[tid][0];
        for (int j = 1; j < 16; ++j) {
            const float d = rdd[tid][j]; const int i2 = rdi[tid][j];
            if (d < bd || (d == bd && i2 < bi)) { bd = d; bi = i2; }
        }
        idxv[tid] = bi;
    }
    __syncthreads();

    float ls = 0.0f;
    float* qb = q + (size_t)n * 128 * HW + p0;
    for (int i = tid; i < 64 * 128; i += 256) {
        const int v = i & 63, c = i >> 6;
        const float e = emb[(size_t)idxv[v] * 128 + c];
        qb[(size_t)c * HW + v] = e;
        const float diff = e - zs[c >> 2][v][c & 3];
        ls = fmaf(diff, diff, ls);
    }
    red[tid] = ls;
    __syncthreads();
    for (int s = 128; s > 0; s >>= 1) {
        if (tid < s) red[tid] += red[tid + s];
        __syncthreads();
    }
    if (tid == 0) lossp[blockIdx.x] = red[0];
}

__global__ void loss_finish_kernel(const float* __restrict__ p, int n, float scale,
                                   float* __restrict__ out)
{
    __shared__ float red[256];
    float s = 0.0f;
    for (int i = threadIdx.x; i < n; i += 256) s += p[i];
    red[threadIdx.x] = s;
    __syncthreads();
    for (int k = 128; k > 0; k >>= 1) {
        if (threadIdx.x < k) red[threadIdx.x] += red[threadIdx.x + k];
        __syncthreads();
    }
    if (threadIdx.x == 0) out[0] = red[0] * scale;
}

// Final 1x1 heads (float4)
__global__ void outconv_kernel(const float* __restrict__ y,
                               const float* __restrict__ odw, const float* __restrict__ odb,
                               const float* __restrict__ orw, const float* __restrict__ orb,
                               float* __restrict__ out)
{
    const int idx = blockIdx.x * TPB + threadIdx.x;
    const int HW4 = 16384;
    if (idx >= 8 * 4 * HW4) return;
    const int p4 = idx & (HW4 - 1);
    const int t = idx >> 14;
    const int c = t & 3, n = t >> 2;
    const float4* yb4 = (const float4*)(y + (size_t)n * 32 * 65536);
    float4 v;
    const int base = (c == 0) ? 0 : 16;
    const float* wv = (c == 0) ? odw : orw + (c - 1) * 16;
    const float b = (c == 0) ? odb[0] : orb[c - 1];
    v.x = b; v.y = b; v.z = b; v.w = b;
    for (int k = 0; k < 16; ++k) {
        const float w = wv[k];
        const float4 f = yb4[(size_t)(base + k) * HW4 + p4];
        v.x = fmaf(f.x, w, v.x); v.y = fmaf(f.y, w, v.y);
        v.z = fmaf(f.z, w, v.z); v.w = fmaf(f.w, w, v.w);
    }
    ((float4*)out)[idx] = v;
}

extern "C" void kernel_launch(void* const* d_in, const int* in_sizes, int n_in,
                              void* d_out, int out_size, void* d_ws, size_t ws_size,
                              hipStream_t stream)
{
    const float* x      = (const float*)d_in[0];
    const float* eb_dw  = (const float*)d_in[1];
    const float* eb_db  = (const float*)d_in[2];
    const float* eb_rw  = (const float*)d_in[3];
    const float* eb_rb  = (const float*)d_in[4];
    const float* eb_c1w = (const float*)d_in[5];
    const float* eb_c1b = (const float*)d_in[6];
    const float* eb_c2w = (const float*)d_in[7];
    const float* eb_c2b = (const float*)d_in[8];
    const float* eb_c3w = (const float*)d_in[9];
    const float* eb_c3b = (const float*)d_in[10];
    const float* eb_rw1 = (const float*)d_in[11];
    const float* eb_rw2 = (const float*)d_in[12];
    const float* et_c1w = (const float*)d_in[13];
    const float* et_c1b = (const float*)d_in[14];
    const float* et_c2w = (const float*)d_in[15];
    const float* et_c2b = (const float*)d_in[16];
    const float* et_rw1 = (const float*)d_in[17];
    const float* et_rw2 = (const float*)d_in[18];
    const float* pvt_w  = (const float*)d_in[19];
    const float* pvt_b  = (const float*)d_in[20];
    const float* up_w   = (const float*)d_in[21];
    const float* up_b   = (const float*)d_in[22];
    const float* pvb_w  = (const float*)d_in[23];
    const float* pvb_b  = (const float*)d_in[24];
    const float* emb_t  = (const float*)d_in[25];
    const float* emb_b  = (const float*)d_in[26];
    const float* db_c1w = (const float*)d_in[27];
    const float* db_c1b = (const float*)d_in[28];
    const float* db_rw1 = (const float*)d_in[29];
    const float* db_rw2 = (const float*)d_in[30];
    const float* db_t1w = (const float*)d_in[31];
    const float* db_t1b = (const float*)d_in[32];
    const float* db_t2w = (const float*)d_in[33];
    const float* db_t2b = (const float*)d_in[34];
    const float* db_odw = (const float*)d_in[35];
    const float* db_odb = (const float*)d_in[36];
    const float* db_orw = (const float*)d_in[37];
    const float* db_orb = (const float*)d_in[38];

    float* ws  = (float*)d_ws;
    float* out = (float*)d_out;

    // ---- workspace arena (float offsets). Round-4 live-range proof.
    const size_t OFF_H0   = 0;
    const size_t OFF_H1   = 33554432;
    const size_t OFF_H2   = 0;
    const size_t OFF_ENCB = 4194304;
    const size_t OFF_RH   = 8388608;
    const size_t OFF_T1   = 10485760;
    const size_t OFF_T2   = 11534336;
    const size_t OFF_ZT   = 12582912;
    const size_t OFF_UPT  = 13631488;
    const size_t OFF_ZB   = 17825792;
    const size_t OFF_Y    = 22020096;
    const size_t OFF_Y1   = 26214400;
    const size_t OFF_Y2   = 0;
    const size_t OFF_ENT  = 34603008;
    const size_t OFF_ENB  = 34605056;
    const size_t OFF_LPT  = 34607104;
    const size_t OFF_LPB  = 34607232;
    const size_t NEED     = 41943680;
    if (ws_size < NEED * sizeof(float)) return;

    // ---- output layout: loss_b, loss_t, recon, q_t, q_b ----
    float* o_loss_b = out + 0;
    float* o_loss_t = out + 1;
    float* o_recon  = out + 2;
    float* o_qt     = out + 2 + 8 * 4 * 65536;
    float* o_qb     = o_qt + 8 * 128 * 1024;

    // ===== EncoderBot =====
    head_kernel<<<8 * 64 * 16384 / TPB, TPB, 0, stream>>>(
        x, eb_dw, eb_db, eb_rw, eb_rb, ws + OFF_H0);
    conv4s2_kernel<128, 2><<<dim3(64, 2, 8), 256, 0, stream>>>(
        ws + OFF_H0, eb_c1w, eb_c1b, ws + OFF_H1, 64, 64, 1);
    conv4s2_kernel<64, 4><<<dim3(16, 4, 8), 256, 0, stream>>>(
        ws + OFF_H1, eb_c2w, eb_c2b, ws + OFF_H2, 64, 128, 1);
    emb_norm_kernel<<<8, TPB, 0, stream>>>(emb_t, ws + OFF_ENT, 2048);
    emb_norm_kernel<<<8, TPB, 0, stream>>>(emb_b, ws + OFF_ENB, 2048);
    conv3_kernel<64, 4, 8, false, false><<<dim3(16, 4, 8), 256, 0, stream>>>(
        ws + OFF_H2, nullptr, eb_c3w, eb_c3b, ws + OFF_ENCB, 128, 128, 0);
    for (int i = 0; i < 2; ++i) {
        conv3_kernel<64, 4, 4, true, false><<<dim3(16, 4, 8), 256, 0, stream>>>(
            ws + OFF_ENCB, nullptr, eb_rw1 + (size_t)i * 64 * 64 * 9, nullptr,
            ws + OFF_RH, 128, 64, 0);
        if (i == 1)
            conv1_kernel<256, true, true, true, false><<<dim3(16, 4, 8), 256, 0, stream>>>(
                ws + OFF_RH, nullptr, eb_rw2 + (size_t)i * 128 * 32, nullptr,
                ws + OFF_ENCB, 64, 128, 4096);
        else
            conv1_kernel<256, true, true, false, false><<<dim3(16, 4, 8), 256, 0, stream>>>(
                ws + OFF_RH, nullptr, eb_rw2 + (size_t)i * 128 * 32, nullptr,
                ws + OFF_ENCB, 64, 128, 4096);
    }

    // ===== EncoderTop =====
    conv4s2_kernel<32, 4><<<dim3(8, 4, 8), 256, 0, stream>>>(
        ws + OFF_ENCB, et_c1w, et_c1b, ws + OFF_T1, 128, 128, 1);
    conv3_kernel<32, 4, 8, false, false><<<dim3(8, 4, 8), 256, 0, stream>>>(
        ws + OFF_T1, nullptr, et_c2w, et_c2b, ws + OFF_T2, 128, 128, 1);
    for (int i = 0; i < 2; ++i) {
        conv3_kernel<32, 4, 4, true, false><<<dim3(8, 4, 8), 256, 0, stream>>>(
            ws + OFF_T2, nullptr, et_rw1 + (size_t)i * 64 * 64 * 9, nullptr,
            ws + OFF_RH, 128, 64, 0);
        if (i == 1)
            conv1_kernel<128, true, true, true, false><<<dim3(8, 4, 8), 256, 0, stream>>>(
                ws + OFF_RH, nullptr, et_rw2 + (size_t)i * 128 * 32, nullptr,
                ws + OFF_T2, 64, 128, 1024);
        else
            conv1_kernel<128, true, true, false, false><<<dim3(8, 4, 8), 256, 0, stream>>>(
                ws + OFF_RH, nullptr, et_rw2 + (size_t)i * 128 * 32, nullptr,
                ws + OFF_T2, 64, 128, 1024);
    }

    // ===== top VQ =====
    conv1_kernel<128, false, false, false, false><<<dim3(8, 4, 8), 256, 0, stream>>>(
        ws + OFF_T2, nullptr, pvt_w, pvt_b, ws + OFF_ZT, 128, 128, 1024);
    vq_kernel<<<128, 256, 0, stream>>>(ws + OFF_ZT, emb_t, ws + OFF_ENT, o_qt,
                                       ws + OFF_LPT, 1024, 2048);
    loss_finish_kernel<<<1, 256, 0, stream>>>(ws + OFF_LPT, 128,
                                              0.25f / (8192.0f * 128.0f), o_loss_t);

    convt4_kernel<64, 4, 32><<<dim3(16, 4, 8), 256, 0, stream>>>(
        o_qt, up_w, up_b, ws + OFF_UPT, 128, 128, 0);

    // ===== PreVQBot / bottom VQ =====
    conv1_kernel<256, false, false, false, true><<<dim3(16, 4, 8), 256, 0, stream>>>(
        ws + OFF_ENCB, ws + OFF_UPT, pvb_w, pvb_b, ws + OFF_ZB, 256, 128, 4096);
    vq_kernel<<<512, 256, 0, stream>>>(ws + OFF_ZB, emb_b, ws + OFF_ENB, o_qb,
                                       ws + OFF_LPB, 4096, 2048);
    loss_finish_kernel<<<1, 256, 0, stream>>>(ws + OFF_LPB, 512,
                                              0.25f / (32768.0f * 128.0f), o_loss_b);

    // ===== DecoderBot =====
    conv3_kernel<64, 4, 8, false, true><<<dim3(16, 4, 8), 256, 0, stream>>>(
        ws + OFF_UPT, o_qb, db_c1w, db_c1b, ws + OFF_Y, 256, 128, 0);
    for (int i = 0; i < 2; ++i) {
        conv3_kernel<64, 4, 4, true, false><<<dim3(16, 4, 8), 256, 0, stream>>>(
            ws + OFF_Y, nullptr, db_rw1 + (size_t)i * 64 * 64 * 9, nullptr,
            ws + OFF_RH, 128, 64, 0);
        if (i == 1)
            conv1_kernel<256, true, true, true, false><<<dim3(16, 4, 8), 256, 0, stream>>>(
                ws + OFF_RH, nullptr, db_rw2 + (size_t)i * 128 * 32, nullptr,
                ws + OFF_Y, 64, 128, 4096);
        else
            conv1_kernel<256, true, true, false, false><<<dim3(16, 4, 8), 256, 0, stream>>>(
                ws + OFF_RH, nullptr, db_rw2 + (size_t)i * 128 * 32, nullptr,
                ws + OFF_Y, 64, 128, 4096);
    }
    convt4_kernel<128, 2, 32><<<dim3(64, 2, 8), 256, 0, stream>>>(
        ws + OFF_Y, db_t1w, db_t1b, ws + OFF_Y1, 128, 64, 1);
    convt4_kernel<256, 2, 16><<<dim3(128, 2, 8), 128, 0, stream>>>(
        ws + OFF_Y1, db_t2w, db_t2b, ws + OFF_Y2, 64, 32, 0);
    outconv_kernel<<<8 * 4 * 16384 / TPB, TPB, 0, stream>>>(
        ws + OFF_Y2, db_odw, db_odb, db_orw, db_orb, o_recon);
}